// Round 8
// baseline (8157.832 us; speedup 1.0000x reference)
//
#include <hip/hip_runtime.h>
#include <stdint.h>

// LSTM forward, B=32 T=2048 D=512 H=512 G=2048.
// Round 8 = round 6 structure (128 WGs, 1 chain/WG, bg=bid&7 XCD-local
// domains, full-K-per-wave MFMA) + working XCD-local exchange:
//   publish = plain store (updates the shared per-XCD L2 line in place;
//             same-XCD consumers see it via sc0 loads ~200-300cy)
//           + sc0sc1 store (write-through to MALL: slow-path correctness
//             even if the bid->XCD round-robin assumption breaks).
//   Plain-first ordering => local L2 line is never older than MALL, so a
//   dirty eviction can never revert MALL to an older tag.
// Polls: sc0 (L1-bypass, local-L2 hit) x12 tries, then sc0sc1 fallback.
// No entry fence: cross-replay stale lines hold bit-identical values
// (deterministic kernel), so they are harmless.

#define B_ 32
#define T_ 2048
#define D_ 512
#define H_ 512
#define G_ 2048
#define NCG 16
#define NBG 8

typedef __attribute__((ext_vector_type(4))) float f32x4;
typedef __attribute__((ext_vector_type(8))) short bf16x8;
typedef __attribute__((ext_vector_type(4))) unsigned int uint4v;
typedef __attribute__((ext_vector_type(2))) unsigned int uint2v;

__device__ __forceinline__ unsigned short f2bf(float f) {
  union { float f; unsigned int u; } v; v.f = f;
  unsigned int r = (v.u + 0x7FFFu + ((v.u >> 16) & 1u)) >> 16;
  return (unsigned short)r;
}
__device__ __forceinline__ float bf2f(unsigned short s) {
  union { unsigned int u; float f; } v; v.u = ((unsigned int)s) << 16;
  return v.f;
}
__device__ __forceinline__ float sigm(float x) { return 1.0f / (1.0f + __expf(-x)); }
__device__ __forceinline__ float tanh_(float x) { return 1.0f - 2.0f / (__expf(2.0f * x) + 1.0f); }

__device__ __forceinline__ void store_x4_coherent(unsigned int* p, uint4v v) {
  asm volatile("global_store_dwordx4 %0, %1, off sc0 sc1" :: "v"(p), "v"(v) : "memory");
}

#define BARRIER_LGKM()                                          \
  do {                                                          \
    asm volatile("s_waitcnt lgkmcnt(0)" ::: "memory");          \
    __builtin_amdgcn_sched_barrier(0);                          \
    __builtin_amdgcn_s_barrier();                               \
    __builtin_amdgcn_sched_barrier(0);                          \
  } while (0)

#define VMWAIT(N)                                               \
  do { asm volatile("s_waitcnt vmcnt(" #N ")" ::: "memory");    \
       __builtin_amdgcn_sched_barrier(0); } while (0)

// ---------------- Phase 1: convert inputs + seed/clear h_tag ----------------
__global__ __launch_bounds__(256) void prep_kernel(
    const float* __restrict__ x, const float* __restrict__ w_ih,
    const float* __restrict__ hx,
    unsigned short* __restrict__ x_bf, unsigned short* __restrict__ w_bf,
    unsigned int* __restrict__ h_tag) {
  const int NX8 = (B_ * T_ * D_) / 8;   // 4,194,304
  const int NWT8 = (G_ * D_) / 8;       // 131,072
  int i = blockIdx.x * 256 + threadIdx.x;
  if (i < NX8) {
    float4 a = reinterpret_cast<const float4*>(x)[i * 2];
    float4 b = reinterpret_cast<const float4*>(x)[i * 2 + 1];
    uint4v v;
    v[0] = (unsigned)f2bf(a.x) | ((unsigned)f2bf(a.y) << 16);
    v[1] = (unsigned)f2bf(a.z) | ((unsigned)f2bf(a.w) << 16);
    v[2] = (unsigned)f2bf(b.x) | ((unsigned)f2bf(b.y) << 16);
    v[3] = (unsigned)f2bf(b.z) | ((unsigned)f2bf(b.w) << 16);
    reinterpret_cast<uint4v*>(x_bf)[i] = v;
  } else if (i < NX8 + NWT8) {
    int j = i - NX8;
    float4 a = reinterpret_cast<const float4*>(w_ih)[j * 2];
    float4 b = reinterpret_cast<const float4*>(w_ih)[j * 2 + 1];
    uint4v v;
    v[0] = (unsigned)f2bf(a.x) | ((unsigned)f2bf(a.y) << 16);
    v[1] = (unsigned)f2bf(a.z) | ((unsigned)f2bf(a.w) << 16);
    v[2] = (unsigned)f2bf(b.x) | ((unsigned)f2bf(b.y) << 16);
    v[3] = (unsigned)f2bf(b.z) | ((unsigned)f2bf(b.w) << 16);
    reinterpret_cast<uint4v*>(w_bf)[j] = v;
  } else if (i < NX8 + NWT8 + 2048) {
    int j = i - NX8 - NWT8;  // seed slot 0 from hx, tag 0
    float4 a = reinterpret_cast<const float4*>(hx)[j * 2];
    float4 b = reinterpret_cast<const float4*>(hx)[j * 2 + 1];
    uint4v v0, v1;
    v0[0] = f2bf(a.x); v0[1] = f2bf(a.y); v0[2] = f2bf(a.z); v0[3] = f2bf(a.w);
    v1[0] = f2bf(b.x); v1[1] = f2bf(b.y); v1[2] = f2bf(b.z); v1[3] = f2bf(b.w);
    unsigned int* p = h_tag + j * 8;
    store_x4_coherent(p, v0);
    store_x4_coherent(p + 4, v1);
  } else {
    int j = i - NX8 - NWT8 - 2048;  // clear slot 1
    unsigned int* p = h_tag + 16384 + j * 8;
    uint4v z = {0u, 0u, 0u, 0u};
    store_x4_coherent(p, z);
    store_x4_coherent(p + 4, z);
  }
}

// ---------------- Phase 2: gx GEMM (unchanged) ----------------
__global__ __launch_bounds__(256, 2) void gemm_gx(
    const unsigned short* __restrict__ x_bf, const unsigned short* __restrict__ w_bf,
    const float* __restrict__ b_ih, const float* __restrict__ b_hh,
    unsigned short* __restrict__ gx_ws) {
  __shared__ unsigned short As[128 * 40];
  __shared__ unsigned short Bs[128 * 40];
  __shared__ unsigned short Eg[128 * 136];
  const int bid = blockIdx.x;
  const int cb = bid & 15, rb = bid >> 4;
  const int r0 = rb * 128, c0 = cb * 128;
  const int tid = threadIdx.x;
  const int lane = tid & 63;
  const int w = tid >> 6;
  const int qr = (w >> 1) * 64, qc = (w & 1) * 64;
  f32x4 acc[4][4] = {};

  for (int kt = 0; kt < 16; ++kt) {
    const int k0 = kt * 32;
    uint4v av[2], bv[2];
#pragma unroll
    for (int c = 0; c < 2; ++c) {
      int flat = c * 256 + tid;
      int row = flat >> 2, q = flat & 3;
      av[c] = *reinterpret_cast<const uint4v*>(x_bf + (size_t)(r0 + row) * 512 + k0 + q * 8);
      bv[c] = *reinterpret_cast<const uint4v*>(w_bf + (size_t)(c0 + row) * 512 + k0 + q * 8);
    }
    __syncthreads();
#pragma unroll
    for (int c = 0; c < 2; ++c) {
      int flat = c * 256 + tid;
      int row = flat >> 2, q = flat & 3;
      *reinterpret_cast<uint4v*>(&As[row * 40 + q * 8]) = av[c];
      *reinterpret_cast<uint4v*>(&Bs[row * 40 + q * 8]) = bv[c];
    }
    __syncthreads();
    bf16x8 af[4], bfr[4];
#pragma unroll
    for (int mt = 0; mt < 4; ++mt)
      af[mt] = *reinterpret_cast<const bf16x8*>(&As[(qr + mt * 16 + (lane & 15)) * 40 + (lane >> 4) * 8]);
#pragma unroll
    for (int nt = 0; nt < 4; ++nt)
      bfr[nt] = *reinterpret_cast<const bf16x8*>(&Bs[(qc + nt * 16 + (lane & 15)) * 40 + (lane >> 4) * 8]);
#pragma unroll
    for (int mt = 0; mt < 4; ++mt)
#pragma unroll
      for (int nt = 0; nt < 4; ++nt)
        acc[mt][nt] = __builtin_amdgcn_mfma_f32_16x16x32_bf16(af[mt], bfr[nt], acc[mt][nt], 0, 0, 0);
  }
  __syncthreads();
#pragma unroll
  for (int nt = 0; nt < 4; ++nt) {
    int cg = c0 + qc + nt * 16 + (lane & 15);
    float bias = b_ih[cg] + b_hh[cg];
#pragma unroll
    for (int mt = 0; mt < 4; ++mt)
#pragma unroll
      for (int j = 0; j < 4; ++j) {
        int tr = qr + mt * 16 + (lane >> 4) * 4 + j;
        int cl = qc + nt * 16 + (lane & 15);
        Eg[tr * 136 + cl] = f2bf(acc[mt][nt][j] + bias);
      }
  }
  __syncthreads();
  const int b = r0 >> 11;
  const int g = c0 >> 9;
  const int t0 = r0 & 2047;
  const int nw0 = (c0 & 511) >> 5;
  const int bg = b >> 2, bq = b & 3;
  for (int c = tid; c < 512; c += 256) {
    int tr = c >> 2, nwi = c & 3;
    size_t dst = (((size_t)(t0 + tr) * NBG + bg) * NCG + (nw0 + nwi)) * 512 + bq * 128 + g * 32;
    const unsigned short* src = &Eg[tr * 136 + nwi * 32];
#pragma unroll
    for (int q = 0; q < 4; ++q)
      *reinterpret_cast<uint4v*>(gx_ws + dst + q * 8) =
          *reinterpret_cast<const uint4v*>(src + q * 8);
  }
}

// ---------------- Phase 3: recurrence ----------------
#define POLL_FAST() \
  asm volatile("global_load_dwordx4 %0, %1, off sc0" : "=v"(hv) : "v"(pollp))
#define POLL_SLOW() \
  asm volatile("global_load_dwordx4 %0, %1, off sc0 sc1" : "=v"(hv) : "v"(pollp))

__global__ __launch_bounds__(512) void lstm_rec(
    const float* __restrict__ cx, const float* __restrict__ w_hh,
    const unsigned short* __restrict__ gx_ws, unsigned int* __restrict__ h_tag,
    float* __restrict__ out) {
  const int bid = blockIdx.x;
  const int bg = bid & 7;    // batch-group == XCD (round-robin heuristic)
  const int nw = bid >> 3;   // col-group
  const int tid = threadIdx.x;
  const int lane = tid & 63;
  const int w = tid >> 6;
  const int gi = w >> 1;
  const int half = w & 1;
  __shared__ unsigned short As[4 * 536];   // h rows (bf16), stride 536
  __shared__ float Gt2[8 * 64];            // [n][cl*4+bq]
  __shared__ unsigned short GxL[2][512];   // gx dbuf [bq][g][jl]

  // B-frags: one N-tile (16 gate-cols), full K=512 -> 16 frags = 64 VGPR
  bf16x8 breg[16];
  {
    int gcol = gi * 512 + nw * 32 + half * 16 + (lane & 15);
    const float* wrow = w_hh + (size_t)gcol * 512;
#pragma unroll
    for (int kk = 0; kk < 16; ++kk) {
      int k = kk * 32 + (lane >> 4) * 8;
      float4 f0 = *reinterpret_cast<const float4*>(wrow + k);
      float4 f1 = *reinterpret_cast<const float4*>(wrow + k + 4);
      uint4v v;
      v[0] = (unsigned)f2bf(f0.x) | ((unsigned)f2bf(f0.y) << 16);
      v[1] = (unsigned)f2bf(f0.z) | ((unsigned)f2bf(f0.w) << 16);
      v[2] = (unsigned)f2bf(f1.x) | ((unsigned)f2bf(f1.y) << 16);
      v[3] = (unsigned)f2bf(f1.z) | ((unsigned)f2bf(f1.w) << 16);
      breg[kk] = __builtin_bit_cast(bf16x8, v);
    }
  }
  // elementwise ownership (waves 0,1): bq=lane&3, cl=lane>>2, jl=w*16+cl
  const int bq = lane & 3;
  const int cl = lane >> 2;
  const int jl = (w & 1) * 16 + cl;
  const int col = nw * 32 + jl;
  const int bno = bg * 4 + bq;
  float c = 0.0f;
  if (w < 2) {
    c = cx[bno * 512 + col];
    asm volatile("" :: "v"(c));  // materialize pre-loop
  }

  unsigned int* slot0 = h_tag;
  unsigned int* slot1 = h_tag + 16384;
  const unsigned int* pollp0 = slot0 + bg * 2048 + tid * 4;
  const unsigned int* pollp1 = slot1 + bg * 2048 + tid * 4;
  const unsigned short* gx_base = gx_ws + ((size_t)bg * NCG + nw) * 512;
  const size_t gx_tstride = (size_t)NBG * NCG * 512;

  uint4v hv;
  uint4v gxr;

  // ---- prologue: gx[0] + poll t=0 (tags seeded 0)
  if (w == 0)
    asm volatile("global_load_dwordx4 %0, %1, off"
                 : "=v"(gxr) : "v"(gx_base + lane * 8));
  {
    const unsigned int* pollp = pollp0;
    POLL_FAST();
    int guard = 0;
    for (;;) {
      VMWAIT(0);
      unsigned bad = (hv[0] >> 16) | (hv[1] >> 16) | (hv[2] >> 16) | (hv[3] >> 16);
      if (!bad || guard > (1 << 20)) break;
      if (++guard < 12) POLL_FAST(); else POLL_SLOW();
    }
    uint2v pk;
    pk[0] = (hv[0] & 0xffffu) | (hv[1] << 16);
    pk[1] = (hv[2] & 0xffffu) | (hv[3] << 16);
    *reinterpret_cast<uint2v*>(&As[(tid >> 7) * 536 + (tid & 127) * 4]) = pk;
  }
  if (w == 0)
    *reinterpret_cast<uint4v*>(&GxL[0][lane * 8]) = __builtin_bit_cast(uint4v, gxr);

  for (int t = 0; t < T_; ++t) {
    BARRIER_LGKM();  // A: As + GxL[t&1] ready
    const bool more = (t + 1 < T_);
    if (w == 0 && more)
      asm volatile("global_load_dwordx4 %0, %1, off"
                   : "=v"(gxr) : "v"(gx_base + (size_t)(t + 1) * gx_tstride + lane * 8));
    // ---- MFMA: full K=512, one N-tile per wave; 2 independent chains
    f32x4 a0 = {}, a1 = {};
#pragma unroll
    for (int kk = 0; kk < 16; kk += 2) {
      bf16x8 af0 = *reinterpret_cast<const bf16x8*>(
          &As[(lane & 3) * 536 + kk * 32 + (lane >> 4) * 8]);
      bf16x8 af1 = *reinterpret_cast<const bf16x8*>(
          &As[(lane & 3) * 536 + (kk + 1) * 32 + (lane >> 4) * 8]);
      a0 = __builtin_amdgcn_mfma_f32_16x16x32_bf16(af0, breg[kk], a0, 0, 0, 0);
      a1 = __builtin_amdgcn_mfma_f32_16x16x32_bf16(af1, breg[kk + 1], a1, 0, 0, 0);
    }
    if (lane < 16) {
      f32x4 s4 = a0 + a1;  // C rows 0-3 = batches 0-3, col = lane
      *reinterpret_cast<f32x4*>(&Gt2[w * 64 + lane * 4]) = s4;
    }
    BARRIER_LGKM();  // B: Gt2 complete
    const unsigned int* pollp = (t & 1) ? pollp0 : pollp1;
    if (w >= 2) {
      if (more) POLL_FAST();
    } else {
      // ---- elementwise (waves 0,1): 128 outputs, 4 LDS reads each
      const int gxb = t & 1;
      float s0 = Gt2[(0 * 2 + w) * 64 + lane] + bf2f(GxL[gxb][bq * 128 + 0 * 32 + jl]);
      float s1 = Gt2[(1 * 2 + w) * 64 + lane] + bf2f(GxL[gxb][bq * 128 + 1 * 32 + jl]);
      float s2 = Gt2[(2 * 2 + w) * 64 + lane] + bf2f(GxL[gxb][bq * 128 + 2 * 32 + jl]);
      float s3 = Gt2[(3 * 2 + w) * 64 + lane] + bf2f(GxL[gxb][bq * 128 + 3 * 32 + jl]);
      float ia = sigm(s0), fa = sigm(s1), ga = tanh_(s2), oa = sigm(s3);
      c = fa * c + ia * ga;
      float h = oa * tanh_(c);
      if (more) {
        // dual publish: plain first (updates shared per-XCD L2 line in
        // place -> same-XCD sc0 polls see it fast), then sc0sc1 (MALL,
        // correctness fallback). Plain-first => L2 never older than MALL.
        unsigned int word = (unsigned int)f2bf(h) | (((unsigned int)(t + 1)) << 16);
        unsigned int* pp = ((t & 1) ? slot0 : slot1) + bno * 512 + col;
        asm volatile("global_store_dword %0, %1, off" :: "v"(pp), "v"(word) : "memory");
        asm volatile("global_store_dword %0, %1, off sc0 sc1" :: "v"(pp), "v"(word) : "memory");
        POLL_FAST();
      }
      size_t bo = (size_t)bno * (T_ * H_) + (size_t)t * H_ + col;
      asm volatile("global_store_dword %0, %1, off" :: "v"(out + bo), "v"(fa) : "memory");
      asm volatile("global_store_dword %0, %1, off"
                   :: "v"(out + (size_t)B_ * T_ * H_ + bo), "v"(h) : "memory");
      asm volatile("global_store_dword %0, %1, off"
                   :: "v"(out + (size_t)2 * B_ * T_ * H_ + bo), "v"(ga) : "memory");
      if (!more) out[(size_t)3 * B_ * T_ * H_ + bno * 512 + col] = oa;
    }
    if (more) {
      // first wait: w<2 FIFO = [gxr?][pubL2][pubMALL][poll][out*3] -> vmcnt(3)
      if (w < 2) VMWAIT(3); else VMWAIT(0);
      const unsigned want = (unsigned)(t + 1);
      unsigned bad = ((hv[0] >> 16) ^ want) | ((hv[1] >> 16) ^ want) |
                     ((hv[2] >> 16) ^ want) | ((hv[3] >> 16) ^ want);
      int guard = 0;
      while (bad) {
        if (++guard < 12) POLL_FAST(); else POLL_SLOW();
        VMWAIT(0);
        bad = ((hv[0] >> 16) ^ want) | ((hv[1] >> 16) ^ want) |
              ((hv[2] >> 16) ^ want) | ((hv[3] >> 16) ^ want);
        if (guard > (1 << 20)) break;
      }
      uint2v pk;
      pk[0] = (hv[0] & 0xffffu) | (hv[1] << 16);
      pk[1] = (hv[2] & 0xffffu) | (hv[3] << 16);
      *reinterpret_cast<uint2v*>(&As[(tid >> 7) * 536 + (tid & 127) * 4]) = pk;
      if (w == 0)
        *reinterpret_cast<uint4v*>(&GxL[(t + 1) & 1][lane * 8]) = __builtin_bit_cast(uint4v, gxr);
    }
  }
}

extern "C" void kernel_launch(void* const* d_in, const int* in_sizes, int n_in,
                              void* d_out, int out_size, void* d_ws, size_t ws_size,
                              hipStream_t stream) {
  const float* x    = (const float*)d_in[0];
  const float* hx   = (const float*)d_in[1];
  const float* cx   = (const float*)d_in[2];
  const float* w_ih = (const float*)d_in[3];
  const float* w_hh = (const float*)d_in[4];
  const float* b_ih = (const float*)d_in[5];
  const float* b_hh = (const float*)d_in[6];
  float* out = (float*)d_out;
  char* ws = (char*)d_ws;
  const size_t OFF_XBF  = 0;                    // 67,108,864
  const size_t OFF_WBF  = 67108864;             //  2,097,152
  const size_t OFF_GX   = 69206016;             // 268,435,456
  const size_t OFF_HTAG = 337641472;            //    131,072
  const size_t NEEDED   = 337772544;
  if (ws_size < NEEDED) return;

  unsigned short* x_bf  = (unsigned short*)(ws + OFF_XBF);
  unsigned short* w_bf  = (unsigned short*)(ws + OFF_WBF);
  unsigned short* gx_ws = (unsigned short*)(ws + OFF_GX);
  unsigned int*   h_tag = (unsigned int*)(ws + OFF_HTAG);

  prep_kernel<<<16912, 256, 0, stream>>>(x, w_ih, hx, x_bf, w_bf, h_tag);
  gemm_gx<<<8192, 256, 0, stream>>>(x_bf, w_bf, b_ih, b_hh, gx_ws);
  lstm_rec<<<128, 512, 0, stream>>>(cx, w_hh, gx_ws, h_tag, out);
}

// Round 9
// 6686.373 us; speedup vs baseline: 1.2201x; 1.2201x over previous
//
#include <hip/hip_runtime.h>
#include <stdint.h>

// LSTM forward, B=32 T=2048 D=512 H=512 G=2048.
// Round 9: gate-interleaved MFMA tiles. Each wave's 16x16 N-tile =
// {i,f,g,o} x 4 h-cols (B cols permuted: gcol = g4*512 + nw*32 + w*4 + cq).
// A rows duplicated mod 4 => every lane's acc[j] = batch j. Elementwise is
// done IN the MFMA wave: 3 cndmask select + 1 shared-exp activation +
// 3 ds_swizzle (xor 4/8/12) gather i,f,g,o into 16 owner lanes/wave, which
// update c and publish directly. Kills barrier B + Gt2 LDS + elem waves.
// Exchange: all sc0sc1 (MALL) tagged dwords; fast-path experiments reverted
// (r6/r8 evidence: no producer-side trick beats the MALL RTT).

#define B_ 32
#define T_ 2048
#define D_ 512
#define H_ 512
#define G_ 2048
#define NCG 16
#define NBG 8

typedef __attribute__((ext_vector_type(4))) float f32x4;
typedef __attribute__((ext_vector_type(8))) short bf16x8;
typedef __attribute__((ext_vector_type(4))) unsigned int uint4v;
typedef __attribute__((ext_vector_type(2))) unsigned int uint2v;

__device__ __forceinline__ unsigned short f2bf(float f) {
  union { float f; unsigned int u; } v; v.f = f;
  unsigned int r = (v.u + 0x7FFFu + ((v.u >> 16) & 1u)) >> 16;
  return (unsigned short)r;
}
__device__ __forceinline__ float bf2f(unsigned short s) {
  union { unsigned int u; float f; } v; v.u = ((unsigned int)s) << 16;
  return v.f;
}
__device__ __forceinline__ float sigm(float x) { return 1.0f / (1.0f + __expf(-x)); }
__device__ __forceinline__ float tanh_(float x) { return 1.0f - 2.0f / (__expf(2.0f * x) + 1.0f); }

__device__ __forceinline__ void store_x4_coherent(unsigned int* p, uint4v v) {
  asm volatile("global_store_dwordx4 %0, %1, off sc0 sc1" :: "v"(p), "v"(v) : "memory");
}

#define BARRIER_LGKM()                                          \
  do {                                                          \
    asm volatile("s_waitcnt lgkmcnt(0)" ::: "memory");          \
    __builtin_amdgcn_sched_barrier(0);                          \
    __builtin_amdgcn_s_barrier();                               \
    __builtin_amdgcn_sched_barrier(0);                          \
  } while (0)

#define VMWAIT(N)                                               \
  do { asm volatile("s_waitcnt vmcnt(" #N ")" ::: "memory");    \
       __builtin_amdgcn_sched_barrier(0); } while (0)

// ---------------- Phase 1: convert inputs + seed/clear h_tag ----------------
__global__ __launch_bounds__(256) void prep_kernel(
    const float* __restrict__ x, const float* __restrict__ w_ih,
    const float* __restrict__ hx,
    unsigned short* __restrict__ x_bf, unsigned short* __restrict__ w_bf,
    unsigned int* __restrict__ h_tag) {
  const int NX8 = (B_ * T_ * D_) / 8;   // 4,194,304
  const int NWT8 = (G_ * D_) / 8;       // 131,072
  int i = blockIdx.x * 256 + threadIdx.x;
  if (i < NX8) {
    float4 a = reinterpret_cast<const float4*>(x)[i * 2];
    float4 b = reinterpret_cast<const float4*>(x)[i * 2 + 1];
    uint4v v;
    v[0] = (unsigned)f2bf(a.x) | ((unsigned)f2bf(a.y) << 16);
    v[1] = (unsigned)f2bf(a.z) | ((unsigned)f2bf(a.w) << 16);
    v[2] = (unsigned)f2bf(b.x) | ((unsigned)f2bf(b.y) << 16);
    v[3] = (unsigned)f2bf(b.z) | ((unsigned)f2bf(b.w) << 16);
    reinterpret_cast<uint4v*>(x_bf)[i] = v;
  } else if (i < NX8 + NWT8) {
    int j = i - NX8;
    float4 a = reinterpret_cast<const float4*>(w_ih)[j * 2];
    float4 b = reinterpret_cast<const float4*>(w_ih)[j * 2 + 1];
    uint4v v;
    v[0] = (unsigned)f2bf(a.x) | ((unsigned)f2bf(a.y) << 16);
    v[1] = (unsigned)f2bf(a.z) | ((unsigned)f2bf(a.w) << 16);
    v[2] = (unsigned)f2bf(b.x) | ((unsigned)f2bf(b.y) << 16);
    v[3] = (unsigned)f2bf(b.z) | ((unsigned)f2bf(b.w) << 16);
    reinterpret_cast<uint4v*>(w_bf)[j] = v;
  } else if (i < NX8 + NWT8 + 2048) {
    int j = i - NX8 - NWT8;  // seed slot 0 from hx, tag 0
    float4 a = reinterpret_cast<const float4*>(hx)[j * 2];
    float4 b = reinterpret_cast<const float4*>(hx)[j * 2 + 1];
    uint4v v0, v1;
    v0[0] = f2bf(a.x); v0[1] = f2bf(a.y); v0[2] = f2bf(a.z); v0[3] = f2bf(a.w);
    v1[0] = f2bf(b.x); v1[1] = f2bf(b.y); v1[2] = f2bf(b.z); v1[3] = f2bf(b.w);
    unsigned int* p = h_tag + j * 8;
    store_x4_coherent(p, v0);
    store_x4_coherent(p + 4, v1);
  } else {
    int j = i - NX8 - NWT8 - 2048;  // clear slot 1
    unsigned int* p = h_tag + 16384 + j * 8;
    uint4v z = {0u, 0u, 0u, 0u};
    store_x4_coherent(p, z);
    store_x4_coherent(p + 4, z);
  }
}

// ---------------- Phase 2: gx GEMM (unchanged) ----------------
__global__ __launch_bounds__(256, 2) void gemm_gx(
    const unsigned short* __restrict__ x_bf, const unsigned short* __restrict__ w_bf,
    const float* __restrict__ b_ih, const float* __restrict__ b_hh,
    unsigned short* __restrict__ gx_ws) {
  __shared__ unsigned short As[128 * 40];
  __shared__ unsigned short Bs[128 * 40];
  __shared__ unsigned short Eg[128 * 136];
  const int bid = blockIdx.x;
  const int cb = bid & 15, rb = bid >> 4;
  const int r0 = rb * 128, c0 = cb * 128;
  const int tid = threadIdx.x;
  const int lane = tid & 63;
  const int w = tid >> 6;
  const int qr = (w >> 1) * 64, qc = (w & 1) * 64;
  f32x4 acc[4][4] = {};

  for (int kt = 0; kt < 16; ++kt) {
    const int k0 = kt * 32;
    uint4v av[2], bv[2];
#pragma unroll
    for (int c = 0; c < 2; ++c) {
      int flat = c * 256 + tid;
      int row = flat >> 2, q = flat & 3;
      av[c] = *reinterpret_cast<const uint4v*>(x_bf + (size_t)(r0 + row) * 512 + k0 + q * 8);
      bv[c] = *reinterpret_cast<const uint4v*>(w_bf + (size_t)(c0 + row) * 512 + k0 + q * 8);
    }
    __syncthreads();
#pragma unroll
    for (int c = 0; c < 2; ++c) {
      int flat = c * 256 + tid;
      int row = flat >> 2, q = flat & 3;
      *reinterpret_cast<uint4v*>(&As[row * 40 + q * 8]) = av[c];
      *reinterpret_cast<uint4v*>(&Bs[row * 40 + q * 8]) = bv[c];
    }
    __syncthreads();
    bf16x8 af[4], bfr[4];
#pragma unroll
    for (int mt = 0; mt < 4; ++mt)
      af[mt] = *reinterpret_cast<const bf16x8*>(&As[(qr + mt * 16 + (lane & 15)) * 40 + (lane >> 4) * 8]);
#pragma unroll
    for (int nt = 0; nt < 4; ++nt)
      bfr[nt] = *reinterpret_cast<const bf16x8*>(&Bs[(qc + nt * 16 + (lane & 15)) * 40 + (lane >> 4) * 8]);
#pragma unroll
    for (int mt = 0; mt < 4; ++mt)
#pragma unroll
      for (int nt = 0; nt < 4; ++nt)
        acc[mt][nt] = __builtin_amdgcn_mfma_f32_16x16x32_bf16(af[mt], bfr[nt], acc[mt][nt], 0, 0, 0);
  }
  __syncthreads();
#pragma unroll
  for (int nt = 0; nt < 4; ++nt) {
    int cg = c0 + qc + nt * 16 + (lane & 15);
    float bias = b_ih[cg] + b_hh[cg];
#pragma unroll
    for (int mt = 0; mt < 4; ++mt)
#pragma unroll
      for (int j = 0; j < 4; ++j) {
        int tr = qr + mt * 16 + (lane >> 4) * 4 + j;
        int cl = qc + nt * 16 + (lane & 15);
        Eg[tr * 136 + cl] = f2bf(acc[mt][nt][j] + bias);
      }
  }
  __syncthreads();
  const int b = r0 >> 11;
  const int g = c0 >> 9;
  const int t0 = r0 & 2047;
  const int nw0 = (c0 & 511) >> 5;
  const int bg = b >> 2, bq = b & 3;
  for (int c = tid; c < 512; c += 256) {
    int tr = c >> 2, nwi = c & 3;
    size_t dst = (((size_t)(t0 + tr) * NBG + bg) * NCG + (nw0 + nwi)) * 512 + bq * 128 + g * 32;
    const unsigned short* src = &Eg[tr * 136 + nwi * 32];
#pragma unroll
    for (int q = 0; q < 4; ++q)
      *reinterpret_cast<uint4v*>(gx_ws + dst + q * 8) =
          *reinterpret_cast<const uint4v*>(src + q * 8);
  }
}

// ---------------- Phase 3: recurrence ----------------
#define POLLQ(PP) \
  asm volatile("global_load_dwordx4 %0, %1, off sc0 sc1" : "=v"(hv) : "v"(PP))

#define SPIN4(PP, WANT)                                                         \
  do {                                                                          \
    unsigned want_ = (unsigned)(WANT);                                          \
    unsigned bad_ = ((hv[0] >> 16) ^ want_) | ((hv[1] >> 16) ^ want_) |         \
                    ((hv[2] >> 16) ^ want_) | ((hv[3] >> 16) ^ want_);          \
    int guard_ = 0;                                                             \
    while (bad_) {                                                              \
      POLLQ(PP);                                                                \
      VMWAIT(0);                                                                \
      bad_ = ((hv[0] >> 16) ^ want_) | ((hv[1] >> 16) ^ want_) |                \
             ((hv[2] >> 16) ^ want_) | ((hv[3] >> 16) ^ want_);                 \
      if (++guard_ > (1 << 20)) break;                                          \
    }                                                                           \
  } while (0)

#define UNPACK_AS()                                                             \
  do {                                                                          \
    uint2v pk_;                                                                 \
    pk_[0] = (hv[0] & 0xffffu) | (hv[1] << 16);                                 \
    pk_[1] = (hv[2] & 0xffffu) | (hv[3] << 16);                                 \
    *reinterpret_cast<uint2v*>(&As[(tid >> 7) * 536 + (tid & 127) * 4]) = pk_;  \
  } while (0)

__global__ __launch_bounds__(512) void lstm_rec(
    const float* __restrict__ cx, const float* __restrict__ w_hh,
    const unsigned short* __restrict__ gx_ws, unsigned int* __restrict__ h_tag,
    float* __restrict__ out) {
  const int bid = blockIdx.x;
  const int bg = bid & 7;    // batch-group (domain)
  const int nw = bid >> 3;   // col-group: h-cols [nw*32, +32)
  const int tid = threadIdx.x;
  const int lane = tid & 63;
  const int w = tid >> 6;
  const int rg = lane >> 4;        // batch owned by this lane's row-group
  const int g4 = (lane >> 2) & 3;  // gate type of this lane's N-col
  const int cq = lane & 3;         // col-in-wave
  const bool owner = (g4 == 0);
  const int col = nw * 32 + w * 4 + cq;
  __shared__ unsigned short As[4 * 536];   // h rows (bf16), stride 536

  // B-frags: N-tile = {i,f,g,o} x 4 cols, full K=512 -> 16 frags = 64 VGPR
  bf16x8 breg[16];
  {
    int gcol = g4 * 512 + col;   // depends only on lane&15 bits -> valid B map
    const float* wrow = w_hh + (size_t)gcol * 512;
#pragma unroll
    for (int kk = 0; kk < 16; ++kk) {
      int k = kk * 32 + (lane >> 4) * 8;
      float4 f0 = *reinterpret_cast<const float4*>(wrow + k);
      float4 f1 = *reinterpret_cast<const float4*>(wrow + k + 4);
      uint4v v;
      v[0] = (unsigned)f2bf(f0.x) | ((unsigned)f2bf(f0.y) << 16);
      v[1] = (unsigned)f2bf(f0.z) | ((unsigned)f2bf(f0.w) << 16);
      v[2] = (unsigned)f2bf(f1.x) | ((unsigned)f2bf(f1.y) << 16);
      v[3] = (unsigned)f2bf(f1.z) | ((unsigned)f2bf(f1.w) << 16);
      breg[kk] = __builtin_bit_cast(bf16x8, v);
    }
  }
  const int bno = bg * 4 + rg;
  float c = 0.0f;
  if (owner) {
    c = cx[bno * 512 + col];
    asm volatile("" :: "v"(c));
  }

  unsigned int* slot0 = h_tag;
  unsigned int* slot1 = h_tag + 16384;
  const unsigned int* pollp0 = slot0 + bg * 2048 + tid * 4;
  const unsigned int* pollp1 = slot1 + bg * 2048 + tid * 4;
  unsigned int* pub0 = slot0 + bno * 512 + col;
  unsigned int* pub1 = slot1 + bno * 512 + col;
  // per-lane gx element address (2B each), layout [t][bg][nw][bq][g4][jl]
  const unsigned short* gx_lane =
      gx_ws + (((size_t)0 * NBG + bg) * NCG + nw) * 512 + rg * 128 + g4 * 32 + (w * 4 + cq);
  const size_t GXT = (size_t)NBG * NCG * 512;  // elements per t
  const size_t BTH = (size_t)B_ * T_ * H_;

  uint4v hv;
  unsigned int gxr = 0, gxn = 0;

  // ---- prologue: gx(0) + poll t=0 (tags seeded 0) + unpack
  asm volatile("global_load_ushort %0, %1, off" : "=v"(gxr) : "v"(gx_lane));
  POLLQ(pollp0);
  VMWAIT(0);
  SPIN4(pollp0, 0u);
  UNPACK_AS();

  for (int t = 0; t < T_; ++t) {
    BARRIER_LGKM();  // As(t) ready for all waves
    const bool more = (t + 1 < T_);
    if (more)
      asm volatile("global_load_ushort %0, %1, off"
                   : "=v"(gxn) : "v"(gx_lane + (size_t)(t + 1) * GXT));
    // ---- MFMA: full K=512, gate-interleaved N-tile; 2 independent chains
    f32x4 a0 = {}, a1 = {};
#pragma unroll
    for (int kk = 0; kk < 16; kk += 2) {
      bf16x8 af0 = *reinterpret_cast<const bf16x8*>(
          &As[(lane & 3) * 536 + kk * 32 + (lane >> 4) * 8]);
      bf16x8 af1 = *reinterpret_cast<const bf16x8*>(
          &As[(lane & 3) * 536 + (kk + 1) * 32 + (lane >> 4) * 8]);
      a0 = __builtin_amdgcn_mfma_f32_16x16x32_bf16(af0, breg[kk], a0, 0, 0, 0);
      a1 = __builtin_amdgcn_mfma_f32_16x16x32_bf16(af1, breg[kk + 1], a1, 0, 0, 0);
    }
    f32x4 s4 = a0 + a1;  // acc[j] = batch j (rows duplicated mod 4)
    // ---- in-wave elementwise (all 64 lanes active)
    float sel = s4[0];
    sel = (rg == 1) ? s4[1] : sel;
    sel = (rg == 2) ? s4[2] : sel;
    sel = (rg == 3) ? s4[3] : sel;
    float s = sel + bf2f((unsigned short)gxr);
    const bool isg = (g4 == 2);
    float xin = isg ? 2.0f * s : s;            // tanh(s) = 2*sigm(2s)-1
    float u = 1.0f / (1.0f + __expf(-xin));
    float act = isg ? 2.0f * u - 1.0f : u;     // i/f/o: sigm; g: tanh
    int ai = __builtin_bit_cast(int, act);
    float fv = __builtin_bit_cast(float, __builtin_amdgcn_ds_swizzle(ai, 0x101F)); // lane^4: f
    float gv = __builtin_bit_cast(float, __builtin_amdgcn_ds_swizzle(ai, 0x201F)); // lane^8: g
    float ov = __builtin_bit_cast(float, __builtin_amdgcn_ds_swizzle(ai, 0x301F)); // lane^12: o
    float h = 0.0f;
    if (owner) {  // 16 owner lanes/wave: (batch rg, col)
      c = fv * c + act * gv;
      h = ov * tanh_(c);
      if (more) {
        unsigned int word = (unsigned int)f2bf(h) | (((unsigned int)(t + 1)) << 16);
        unsigned int* q_ = ((t + 1) & 1) ? pub1 : pub0;
        asm volatile("global_store_dword %0, %1, off sc0 sc1" :: "v"(q_), "v"(word) : "memory");
      }
    }
    if (more) POLLQ((t + 1) & 1 ? pollp1 : pollp0);  // all lanes poll next step
    if (owner) {
      size_t bo = (size_t)bno * (T_ * H_) + (size_t)t * H_ + col;
      const float* pf = out + bo;
      const float* ph = out + BTH + bo;
      const float* pg = out + 2 * BTH + bo;
      asm volatile("global_store_dword %0, %1, off" :: "v"(pf), "v"(fv) : "memory");
      asm volatile("global_store_dword %0, %1, off" :: "v"(ph), "v"(h) : "memory");
      asm volatile("global_store_dword %0, %1, off" :: "v"(pg), "v"(gv) : "memory");
      if (!more) {
        const float* po = out + 3 * BTH + (size_t)bno * H_ + col;
        asm volatile("global_store_dword %0, %1, off" :: "v"(po), "v"(ov) : "memory");
      }
    }
    BARRIER_LGKM();  // all As(t) reads complete -> safe to overwrite
    if (more) {
      // per-wave FIFO: [gxn][pub][poll][out x3] -> vmcnt(3) retires poll
      VMWAIT(3);
      const unsigned int* pb = ((t + 1) & 1) ? pollp1 : pollp0;
      SPIN4(pb, t + 1);
      UNPACK_AS();
      gxr = gxn;
    }
  }
}

extern "C" void kernel_launch(void* const* d_in, const int* in_sizes, int n_in,
                              void* d_out, int out_size, void* d_ws, size_t ws_size,
                              hipStream_t stream) {
  const float* x    = (const float*)d_in[0];
  const float* hx   = (const float*)d_in[1];
  const float* cx   = (const float*)d_in[2];
  const float* w_ih = (const float*)d_in[3];
  const float* w_hh = (const float*)d_in[4];
  const float* b_ih = (const float*)d_in[5];
  const float* b_hh = (const float*)d_in[6];
  float* out = (float*)d_out;
  char* ws = (char*)d_ws;
  const size_t OFF_XBF  = 0;                    // 67,108,864
  const size_t OFF_WBF  = 67108864;             //  2,097,152
  const size_t OFF_GX   = 69206016;             // 268,435,456
  const size_t OFF_HTAG = 337641472;            //    131,072
  const size_t NEEDED   = 337772544;
  if (ws_size < NEEDED) return;

  unsigned short* x_bf  = (unsigned short*)(ws + OFF_XBF);
  unsigned short* w_bf  = (unsigned short*)(ws + OFF_WBF);
  unsigned short* gx_ws = (unsigned short*)(ws + OFF_GX);
  unsigned int*   h_tag = (unsigned int*)(ws + OFF_HTAG);

  prep_kernel<<<16912, 256, 0, stream>>>(x, w_ih, hx, x_bf, w_bf, h_tag);
  gemm_gx<<<8192, 256, 0, stream>>>(x_bf, w_bf, b_ih, b_hh, gx_ws);
  lstm_rec<<<128, 512, 0, stream>>>(cx, w_hh, gx_ws, h_tag, out);
}